// Round 19
// baseline (464.687 us; speedup 1.0000x reference)
//
#include <hip/hip_runtime.h>
#include <hip/hip_bf16.h>
#include <stdint.h>

// Problem constants (QuantizedLinear_15985868276124)
#define IN_F   4096                 // bytes per i8 row == elements
#define OUT_F  11008
#define M_TOK  8192

typedef __attribute__((ext_vector_type(4))) int   int32x4;

// ---------- kernel 1: merged prep — quantize x rows AND W rows ----------
__global__ __launch_bounds__(256) void k_prep(
        const float* __restrict__ x,
        const int* __restrict__ codes,
        const float* __restrict__ codebooks,
        const float* __restrict__ scales,
        signed char* __restrict__ Xq, float* __restrict__ sx,
        signed char* __restrict__ Wq, float* __restrict__ sw) {
    __shared__ float cb[4096];
    __shared__ float red[256];
    int t = threadIdx.x;

    if (blockIdx.x < M_TOK) {
        int r = blockIdx.x;
        const float4* xr = (const float4*)(x + (size_t)r * IN_F) + t * 4;
        float4 v0 = xr[0], v1 = xr[1], v2 = xr[2], v3 = xr[3];
        float m = 0.f;
#define MX4(v) m = fmaxf(m, fmaxf(fmaxf(fabsf(v.x), fabsf(v.y)), fmaxf(fabsf(v.z), fabsf(v.w))))
        MX4(v0); MX4(v1); MX4(v2); MX4(v3);
        red[t] = m; __syncthreads();
        for (int s = 128; s > 0; s >>= 1) {
            if (t < s) red[t] = fmaxf(red[t], red[t + s]);
            __syncthreads();
        }
        float rm = fmaxf(red[0], 1e-8f);
        if (t == 0) sx[r] = rm / 127.f;
        float inv = 127.f / rm;
        union { signed char c[16]; uint4 u; } pk;
#define Q4(v, o) pk.c[o] = (signed char)__float2int_rn(v.x * inv);            \
                 pk.c[o+1] = (signed char)__float2int_rn(v.y * inv);          \
                 pk.c[o+2] = (signed char)__float2int_rn(v.z * inv);          \
                 pk.c[o+3] = (signed char)__float2int_rn(v.w * inv)
        Q4(v0, 0); Q4(v1, 4); Q4(v2, 8); Q4(v3, 12);
        *(uint4*)(Xq + (size_t)r * IN_F + t * 16) = pk.u;
    } else {
        int o = blockIdx.x - M_TOK;
        {
            const float4* cbg = (const float4*)codebooks;
            float4* cbl = (float4*)cb;
#pragma unroll
            for (int i = 0; i < 4; ++i) cbl[t + i * 256] = cbg[t + i * 256];
        }
        __syncthreads();
        const int2* cp = (const int2*)codes + (size_t)o * 512 + t * 2;
        int2 c0 = cp[0], c1 = cp[1];
        float e[16]; float m = 0.f;
#pragma unroll
        for (int j = 0; j < 8; ++j) {
            e[j]     = cb[c0.x * 8 + j] + cb[2048 + c0.y * 8 + j];
            e[8 + j] = cb[c1.x * 8 + j] + cb[2048 + c1.y * 8 + j];
        }
#pragma unroll
        for (int j = 0; j < 16; ++j) m = fmaxf(m, fabsf(e[j]));
        red[t] = m; __syncthreads();
        for (int s = 128; s > 0; s >>= 1) {
            if (t < s) red[t] = fmaxf(red[t], red[t + s]);
            __syncthreads();
        }
        float rm = fmaxf(red[0], 1e-8f);
        if (t == 0) sw[o] = scales[o] * rm / 127.f;
        float inv = 127.f / rm;
        union { signed char c[16]; uint4 u; } pk;
#pragma unroll
        for (int j = 0; j < 16; ++j) pk.c[j] = (signed char)__float2int_rn(e[j] * inv);
        *(uint4*)(Wq + (size_t)o * IN_F + t * 16) = pk.u;
    }
}

// ---------- kernel 2: 256x256 i8 GEMM, rotation + SGB-pinned interleave ----
// R19 = R17 rotation (QUAD consumes reads issued >=1 region earlier) +
// sched_group_barrier pinning {4xMFMA, kxDS_READ[,VMEM]}x4 per region.
// Mechanism: MFMA pipe accepts 1 instr/~20cyc; pinned interleave fills each
// stall window with the wave's OWN independent next-phase ds_reads ->
// LDS(2304 cyc/CU) drains under MFMA(2611 cyc/SIMD) instead of after it.
// R17 was null because the compiler hoisted the reads above the MFMA
// cluster (unpinned emission) — reconstructing the serialized pattern.
// No setprio (R18: -13us). Region/ledger protocol identical to R17.

#define BARRIER() __builtin_amdgcn_s_barrier()
#define VMW(n)    asm volatile("s_waitcnt vmcnt(" #n ")")
#define SGB(mask, n) __builtin_amdgcn_sched_group_barrier(mask, n, 0)

// region pin patterns (16 MFMA each; reads/stages per region type)
#define PIN_M16_D4()  do { SGB(8,4); SGB(0x100,1); SGB(8,4); SGB(0x100,1);   \
                           SGB(8,4); SGB(0x100,1); SGB(8,4); SGB(0x100,1); } while (0)
#define PIN_M16_D8()  do { SGB(8,4); SGB(0x100,2); SGB(8,4); SGB(0x100,2);   \
                           SGB(8,4); SGB(0x100,2); SGB(8,4); SGB(0x100,2); } while (0)
#define PIN_M16_V4()  do { SGB(8,4); SGB(0x10,1);  SGB(8,4); SGB(0x10,1);    \
                           SGB(8,4); SGB(0x10,1);  SGB(8,4); SGB(0x10,1); } while (0)
#define PIN_M16_D12_V4() do { SGB(8,4); SGB(0x100,3); SGB(0x10,1);           \
                              SGB(8,4); SGB(0x100,3); SGB(0x10,1);           \
                              SGB(8,4); SGB(0x100,3); SGB(0x10,1);           \
                              SGB(8,4); SGB(0x100,3); SGB(0x10,1); } while (0)

#define GL16(gp, lp) __builtin_amdgcn_global_load_lds(                        \
    (const __attribute__((address_space(1))) void*)(gp),                      \
    (__attribute__((address_space(3))) void*)(lp), 16, 0, 0)

__global__ __launch_bounds__(512, 2) void k_gemm(
        const signed char* __restrict__ A,   // [M_TOK][IN_F] i8
        const signed char* __restrict__ B,   // [OUT_F][IN_F] i8 (B^T layout)
        const float* __restrict__ sx,        // [M_TOK]
        const float* __restrict__ sw,        // [OUT_F]
        const float* __restrict__ bias,
        float* __restrict__ out) {
    __shared__ signed char lA0[256 * 128];   // 32 KiB each
    __shared__ signed char lA1[256 * 128];
    __shared__ signed char lB0[256 * 128];
    __shared__ signed char lB1[256 * 128];

    const int tid = threadIdx.x;
    const int l = tid & 63;
    const int w = tid >> 6;            // wave 0..7
    const int wm = w >> 2, wn = w & 3; // 2 x 4 wave grid; wave tile 128x64

    // T1: bijective XCD swizzle. grid 1376 = 8 XCD * (4 row-chunks * 43 cols)
    int lid = blockIdx.x;
    int xcd = lid & 7, j = lid >> 3;
    int bx = j >> 2;                   // col block 0..42
    int by = (xcd << 2) + (j & 3);     // row block 0..31
    const int rowBase = by * 256;
    const int colBase = bx * 256;

    // ---- staging addressing (swizzle on GLOBAL source; LDS linear)
    const int srow = w * 8 + (l >> 3);
    const int scol = ((l & 7) ^ ((l >> 3) & 7)) << 4;   // byte offset in row
    const signed char* gA = A + (size_t)(rowBase + srow) * IN_F + scol;
    const signed char* gB = B + (size_t)(colBase + srow) * IN_F + scol;
    signed char* lA0w = &lA0[w * 8 * 128];
    signed char* lA1w = &lA1[w * 8 * 128];
    signed char* lB0w = &lB0[w * 8 * 128];
    signed char* lB1w = &lB1[w * 8 * 128];

    // stage half of K-tile t into buffer P: H=0 -> A rows, H=1 -> B rows.
#define STAGEH_(P, t, H) do {                                                 \
    const signed char* _g = ((H) ? gB : gA) + (size_t)(t) * 128;              \
    signed char* _l = ((H) ? lB##P##w : lA##P##w);                            \
    GL16(_g,                       _l);                                       \
    GL16(_g +  64 * IN_F,          _l +  64 * 128);                           \
    GL16(_g + 128 * IN_F,          _l + 128 * 128);                           \
    GL16(_g + 192 * IN_F,          _l + 192 * 128);                           \
} while (0)

    // ---- fragment reads
    const int frow = l & 15, g = l >> 4;
    const int cho0 = ((g ^ (frow & 7)) << 4);
    const int cho1 = (((4 + g) ^ (frow & 7)) << 4);
    const char* rowA0 = (const char*)&lA0[(wm * 128 + frow) * 128];
    const char* rowA1 = (const char*)&lA1[(wm * 128 + frow) * 128];
    const char* rowB0 = (const char*)&lB0[(wn * 64 + frow) * 128];
    const char* rowB1 = (const char*)&lB1[(wn * 64 + frow) * 128];
#define LDA_(P, m, kk) (*(const int32x4*)(rowA##P + (m) * 2048 + ((kk) ? cho1 : cho0)))
#define LDB_(P, n, kk) (*(const int32x4*)(rowB##P + (n) * 2048 + ((kk) ? cho1 : cho0)))

    int32x4 acc[8][4] = {};
    int32x4 ar[4][2];    // ar03 OR ar47 of current tile (time-shared)
    int32x4 brA[2][2];   // br01 of current tile
    int32x4 brB[2][2];   // br23 of current tile

#define QUADQ(M0, N0, BR) do {                                                \
    _Pragma("unroll") for (int mm = 0; mm < 4; ++mm)                          \
    _Pragma("unroll") for (int nn = 0; nn < 2; ++nn)                          \
    _Pragma("unroll") for (int kk = 0; kk < 2; ++kk)                          \
        acc[(M0) + mm][(N0) + nn] = __builtin_amdgcn_mfma_i32_16x16x64_i8(    \
            ar[mm][kk], BR[nn][kk], acc[(M0) + mm][(N0) + nn], 0, 0, 0);      \
} while (0)

#define RD_AR03(P) do {                                                       \
    _Pragma("unroll") for (int mm = 0; mm < 4; ++mm) {                        \
        ar[mm][0] = LDA_(P, mm, 0); ar[mm][1] = LDA_(P, mm, 1); }             \
} while (0)
#define RD_AR47(P) do {                                                       \
    _Pragma("unroll") for (int mm = 0; mm < 4; ++mm) {                        \
        ar[mm][0] = LDA_(P, 4 + mm, 0); ar[mm][1] = LDA_(P, 4 + mm, 1); }     \
} while (0)
#define RD_BR01(P) do {                                                       \
    brA[0][0] = LDB_(P, 0, 0); brA[0][1] = LDB_(P, 0, 1);                     \
    brA[1][0] = LDB_(P, 1, 0); brA[1][1] = LDB_(P, 1, 1);                     \
} while (0)
#define RD_BR23(P) do {                                                       \
    brB[0][0] = LDB_(P, 2, 0); brB[0][1] = LDB_(P, 2, 1);                     \
    brB[1][0] = LDB_(P, 3, 0); brB[1][1] = LDB_(P, 3, 1);                     \
} while (0)

    // prologue: stage t0 full (buf0) + t1 B-half (buf1); VMW(4) retires t0;
    // barrier publishes t0. Then R1(0) without QD: reads + stage t1 A-half.
    STAGEH_(0, 0, 0); STAGEH_(0, 0, 1);
    STAGEH_(1, 1, 1);
    VMW(4); BARRIER();
    RD_AR03(0); RD_BR01(0);
    STAGEH_(1, 1, 0);
    BARRIER();

    // main loop: 15 iterations, pairs (t,t+1) = (0,1)..(28,29).
    for (int i = 0; i < 15; ++i) {
        int t = 2 * i;
        // R2: QA(t); rd br23(t)                       [16 MFMA, 4 DS_READ]
        QUADQ(0, 0, brA);
        RD_BR23(0);
        PIN_M16_D4();
        BARRIER();
        // R3: QB(t); rd ar47(t)                       [16 MFMA, 8 DS_READ]
        QUADQ(0, 2, brB);
        RD_AR47(0);
        PIN_M16_D8();
        BARRIER();
        // R4: QC(t); stage (t+2)B -> lB0; VMW(4)      [16 MFMA, 4 VMEM]
        QUADQ(4, 2, brB);
        STAGEH_(0, t + 2, 1);
        PIN_M16_V4();
        VMW(4); BARRIER();                    // publishes t+1
        // R5: QD(t); rd ar03/br01(t+1); stage (t+2)A  [16 MFMA, 12 DS, 4 VMEM]
        QUADQ(4, 0, brA);
        RD_AR03(1); RD_BR01(1);
        STAGEH_(0, t + 2, 0);
        PIN_M16_D12_V4();
        BARRIER();
        // R6: QA(t+1); rd br23(t+1)
        QUADQ(0, 0, brA);
        RD_BR23(1);
        PIN_M16_D4();
        BARRIER();
        // R7: QB(t+1); rd ar47(t+1)
        QUADQ(0, 2, brB);
        RD_AR47(1);
        PIN_M16_D8();
        BARRIER();
        // R8: QC(t+1); stage (t+3)B -> lB1; VMW(4)
        QUADQ(4, 2, brB);
        STAGEH_(1, t + 3, 1);
        PIN_M16_V4();
        VMW(4); BARRIER();                    // publishes t+2
        // R1next: QD(t+1); rd ar03/br01(t+2); stage (t+3)A -> lA1
        QUADQ(4, 0, brA);
        RD_AR03(0); RD_BR01(0);
        STAGEH_(1, t + 3, 0);
        PIN_M16_D12_V4();
        BARRIER();
    }

    // tail: pair (30,31). Entering: ar=ar03(30), brA=br01(30);
    // outstanding loads = 31B(4) + 31A(4).
    QUADQ(0, 0, brA);            // QA(30)
    RD_BR23(0);
    BARRIER();
    QUADQ(0, 2, brB);            // QB(30)
    RD_AR47(0);
    BARRIER();
    QUADQ(4, 2, brB);            // QC(30)
    VMW(0); BARRIER();           // retires + publishes tile 31
    QUADQ(4, 0, brA);            // QD(30)
    RD_AR03(1); RD_BR01(1);
    BARRIER();
    QUADQ(0, 0, brA);            // QA(31)
    RD_BR23(1);
    BARRIER();
    QUADQ(0, 2, brB);            // QB(31)
    RD_AR47(1);
    BARRIER();
    QUADQ(4, 2, brB);            // QC(31)
    QUADQ(4, 0, brA);            // QD(31)

    // epilogue: C/D layout col = lane&15, row = (lane>>4)*4 + jj
#pragma unroll
    for (int n = 0; n < 4; ++n) {
        int gcol = colBase + wn * 64 + n * 16 + frow;
        float swv = sw[gcol];
        float bv = bias[gcol];
#pragma unroll
        for (int m = 0; m < 8; ++m) {
            int grow0 = rowBase + wm * 128 + m * 16 + g * 4;
            float4 sx4 = *(const float4*)&sx[grow0];
            out[(size_t)(grow0 + 0) * OUT_F + gcol] = (float)acc[m][n][0] * sx4.x * swv + bv;
            out[(size_t)(grow0 + 1) * OUT_F + gcol] = (float)acc[m][n][1] * sx4.y * swv + bv;
            out[(size_t)(grow0 + 2) * OUT_F + gcol] = (float)acc[m][n][2] * sx4.z * swv + bv;
            out[(size_t)(grow0 + 3) * OUT_F + gcol] = (float)acc[m][n][3] * sx4.w * swv + bv;
        }
    }
}

// ---------- launch ----------
extern "C" void kernel_launch(void* const* d_in, const int* in_sizes, int n_in,
                              void* d_out, int out_size, void* d_ws, size_t ws_size,
                              hipStream_t stream) {
    const float* x         = (const float*)d_in[0];
    const int*   codes     = (const int*)d_in[1];
    const float* codebooks = (const float*)d_in[2];
    const float* scales    = (const float*)d_in[3];
    const float* bias      = (const float*)d_in[4];
    float* out = (float*)d_out;

    // workspace: Wq i8 [OUT_F][IN_F]; Xq i8 [M_TOK][IN_F]; sx; sw (~78.7 MB)
    signed char* Wq = (signed char*)d_ws;
    signed char* Xq = Wq + (size_t)OUT_F * IN_F;
    float* sx = (float*)(Xq + (size_t)M_TOK * IN_F);
    float* sw = sx + M_TOK;

    k_prep<<<M_TOK + OUT_F, 256, 0, stream>>>(x, codes, codebooks, scales,
                                              Xq, sx, Wq, sw);
    // grid: (8192/256) * (11008/256) = 32 * 43 = 1376 blocks, 512 threads
    k_gemm<<<1376, 512, 0, stream>>>(Xq, Wq, sx, sw, bias, out);
}

// Round 20
// 458.715 us; speedup vs baseline: 1.0130x; 1.0130x over previous
//
#include <hip/hip_runtime.h>
#include <hip/hip_bf16.h>
#include <stdint.h>

// Problem constants (QuantizedLinear_15985868276124)
#define IN_F   4096                 // bytes per i8 row == elements
#define OUT_F  11008
#define M_TOK  8192

typedef __attribute__((ext_vector_type(4))) int   int32x4;

// ---------- kernel 1: merged prep — quantize x rows AND W rows ----------
__global__ __launch_bounds__(256) void k_prep(
        const float* __restrict__ x,
        const int* __restrict__ codes,
        const float* __restrict__ codebooks,
        const float* __restrict__ scales,
        signed char* __restrict__ Xq, float* __restrict__ sx,
        signed char* __restrict__ Wq, float* __restrict__ sw) {
    __shared__ float cb[4096];
    __shared__ float red[256];
    int t = threadIdx.x;

    if (blockIdx.x < M_TOK) {
        int r = blockIdx.x;
        const float4* xr = (const float4*)(x + (size_t)r * IN_F) + t * 4;
        float4 v0 = xr[0], v1 = xr[1], v2 = xr[2], v3 = xr[3];
        float m = 0.f;
#define MX4(v) m = fmaxf(m, fmaxf(fmaxf(fabsf(v.x), fabsf(v.y)), fmaxf(fabsf(v.z), fabsf(v.w))))
        MX4(v0); MX4(v1); MX4(v2); MX4(v3);
        red[t] = m; __syncthreads();
        for (int s = 128; s > 0; s >>= 1) {
            if (t < s) red[t] = fmaxf(red[t], red[t + s]);
            __syncthreads();
        }
        float rm = fmaxf(red[0], 1e-8f);
        if (t == 0) sx[r] = rm / 127.f;
        float inv = 127.f / rm;
        union { signed char c[16]; uint4 u; } pk;
#define Q4(v, o) pk.c[o] = (signed char)__float2int_rn(v.x * inv);            \
                 pk.c[o+1] = (signed char)__float2int_rn(v.y * inv);          \
                 pk.c[o+2] = (signed char)__float2int_rn(v.z * inv);          \
                 pk.c[o+3] = (signed char)__float2int_rn(v.w * inv)
        Q4(v0, 0); Q4(v1, 4); Q4(v2, 8); Q4(v3, 12);
        *(uint4*)(Xq + (size_t)r * IN_F + t * 16) = pk.u;
    } else {
        int o = blockIdx.x - M_TOK;
        {
            const float4* cbg = (const float4*)codebooks;
            float4* cbl = (float4*)cb;
#pragma unroll
            for (int i = 0; i < 4; ++i) cbl[t + i * 256] = cbg[t + i * 256];
        }
        __syncthreads();
        const int2* cp = (const int2*)codes + (size_t)o * 512 + t * 2;
        int2 c0 = cp[0], c1 = cp[1];
        float e[16]; float m = 0.f;
#pragma unroll
        for (int j = 0; j < 8; ++j) {
            e[j]     = cb[c0.x * 8 + j] + cb[2048 + c0.y * 8 + j];
            e[8 + j] = cb[c1.x * 8 + j] + cb[2048 + c1.y * 8 + j];
        }
#pragma unroll
        for (int j = 0; j < 16; ++j) m = fmaxf(m, fabsf(e[j]));
        red[t] = m; __syncthreads();
        for (int s = 128; s > 0; s >>= 1) {
            if (t < s) red[t] = fmaxf(red[t], red[t + s]);
            __syncthreads();
        }
        float rm = fmaxf(red[0], 1e-8f);
        if (t == 0) sw[o] = scales[o] * rm / 127.f;
        float inv = 127.f / rm;
        union { signed char c[16]; uint4 u; } pk;
#pragma unroll
        for (int j = 0; j < 16; ++j) pk.c[j] = (signed char)__float2int_rn(e[j] * inv);
        *(uint4*)(Wq + (size_t)o * IN_F + t * 16) = pk.u;
    }
}

// ---------- kernel 2: 128x256 i8 GEMM, 4 waves, 2 blocks/CU ----------
// R20: TLP instead of intra-block pipelining. Two independent barrier
// domains per CU; one block's read/stage windows overlap the other's MFMA
// bursts (m114 cross-wave pipe overlap). Per-CU LDS traffic and MFMA work
// identical to R14 (A-reuse 2x, B-reuse 2x). Register budget engineered to
// fit 2 waves/SIMD: acc 128 + ar 32 + brH 32 (N-halves time-share) ~ 220.
// R15 lesson applied: launch_bounds(256,2) -> 256-reg cap (NOT 128).
// LDS: lA[128][128] + lB[256][128] = 48 KiB single-buffer -> 96 KiB/CU.

#define BARRIER() __builtin_amdgcn_s_barrier()
#define VMW0()    asm volatile("s_waitcnt vmcnt(0)")
#define LGKM0()   asm volatile("s_waitcnt lgkmcnt(0)")

#define GL16(gp, lp) __builtin_amdgcn_global_load_lds(                        \
    (const __attribute__((address_space(1))) void*)(gp),                      \
    (__attribute__((address_space(3))) void*)(lp), 16, 0, 0)

__global__ __launch_bounds__(256, 2) void k_gemm(
        const signed char* __restrict__ A,   // [M_TOK][IN_F] i8
        const signed char* __restrict__ B,   // [OUT_F][IN_F] i8 (B^T layout)
        const float* __restrict__ sx,        // [M_TOK]
        const float* __restrict__ sw,        // [OUT_F]
        const float* __restrict__ bias,
        float* __restrict__ out) {
    __shared__ signed char lA[128 * 128];   // 16 KiB
    __shared__ signed char lB[256 * 128];   // 32 KiB

    const int tid = threadIdx.x;
    const int l = tid & 63;
    const int w = tid >> 6;            // wave 0..3
    const int wm = w >> 1, wn = w & 1; // 2 x 2 wave grid; wave tile 64x128

    // T1: XCD swizzle. grid 2752 = 8 XCD * (43 cols * 8 row-segs)
    int lid = blockIdx.x;
    int xcd = lid & 7, j = lid >> 3;   // j in [0,344)
    int bx = j >> 3;                   // col block 0..42
    int by = (xcd << 3) + (j & 7);     // row block 0..63
    const int rowBase = by * 128;
    const int colBase = bx * 256;

    // ---- staging addressing (swizzle on GLOBAL source; LDS linear)
    // wave w: A rows [w*32, w*32+32) (4 GL16), B rows [w*64, w*64+64) (8 GL16)
    const int scol = ((l & 7) ^ ((l >> 3) & 7)) << 4;   // byte offset in row
    const int sA = w * 32 + (l >> 3);
    const int sB = w * 64 + (l >> 3);
    const signed char* gA = A + (size_t)(rowBase + sA) * IN_F + scol;
    const signed char* gB = B + (size_t)(colBase + sB) * IN_F + scol;
    signed char* lAw = &lA[sA * 128 - (l >> 3) * 128];   // wave base (HW adds lane*16)
    signed char* lBw = &lB[sB * 128 - (l >> 3) * 128];

#define STAGE_T(t) do {                                                       \
    const signed char* _ga = gA + (size_t)(t) * 128;                          \
    const signed char* _gb = gB + (size_t)(t) * 128;                          \
    _Pragma("unroll") for (int i = 0; i < 4; ++i)                             \
        GL16(_ga + (size_t)(i * 8) * IN_F, lAw + i * 8 * 128);                \
    _Pragma("unroll") for (int i = 0; i < 8; ++i)                             \
        GL16(_gb + (size_t)(i * 8) * IN_F, lBw + i * 8 * 128);                \
} while (0)

    // ---- fragment reads: chunk = (kk*4 + g) ^ (row&7), row&7 == frow&7
    const int frow = l & 15, g = l >> 4;
    const int cho0 = ((g ^ (frow & 7)) << 4);
    const int cho1 = (((4 + g) ^ (frow & 7)) << 4);
    const char* rowA = (const char*)&lA[(wm * 64 + frow) * 128];
    const char* rowB = (const char*)&lB[(wn * 128 + frow) * 128];
#define LDA_(m, kk) (*(const int32x4*)(rowA + (m) * 2048 + ((kk) ? cho1 : cho0)))
#define LDB_(h, n, kk) (*(const int32x4*)(rowB + (h) * 8192 + (n) * 2048 + ((kk) ? cho1 : cho0)))

    int32x4 acc[4][8] = {};
    int32x4 ar[4][2];    // A frags (64 rows)
    int32x4 brH[4][2];   // B frags, one N-half (64 cols) at a time

    // one N-half: 4M x 4N x 2kk = 32 MFMA
#define QUADH(H) do {                                                         \
    _Pragma("unroll") for (int mm = 0; mm < 4; ++mm)                          \
    _Pragma("unroll") for (int nn = 0; nn < 4; ++nn)                          \
    _Pragma("unroll") for (int kk = 0; kk < 2; ++kk)                          \
        acc[mm][(H) * 4 + nn] = __builtin_amdgcn_mfma_i32_16x16x64_i8(        \
            ar[mm][kk], brH[nn][kk], acc[mm][(H) * 4 + nn], 0, 0, 0);         \
} while (0)

#define RD_AR() do {                                                          \
    _Pragma("unroll") for (int mm = 0; mm < 4; ++mm) {                        \
        ar[mm][0] = LDA_(mm, 0); ar[mm][1] = LDA_(mm, 1); }                   \
} while (0)
#define RD_BRH(H) do {                                                        \
    _Pragma("unroll") for (int nn = 0; nn < 4; ++nn) {                        \
        brH[nn][0] = LDB_(H, nn, 0); brH[nn][1] = LDB_(H, nn, 1); }           \
} while (0)

    // prologue: stage tile0; publish
    STAGE_T(0);
    VMW0(); BARRIER();

    // main loop: 32 K-tiles of 128 bytes
    for (int t = 0; t < 32; ++t) {
        // reads + first N-half MFMA
        RD_AR(); RD_BRH(0);
        QUADH(0);
        RD_BRH(1);
        // all reads of tile t drained across all waves, then overwrite
        LGKM0(); BARRIER();
        if (t < 31) STAGE_T(t + 1);
        QUADH(1);                  // register-resident; covers load flight
        VMW0(); BARRIER();         // publish t+1
    }

    // epilogue: C/D layout col = lane&15, row = (lane>>4)*4 + jj
    // out = sx[row]*sw[col]*acc + bias[col]
#pragma unroll
    for (int n = 0; n < 8; ++n) {
        int gcol = colBase + wn * 128 + n * 16 + frow;
        float swv = sw[gcol];
        float bv = bias[gcol];
#pragma unroll
        for (int m = 0; m < 4; ++m) {
            int grow0 = rowBase + wm * 64 + m * 16 + g * 4;
            float4 sx4 = *(const float4*)&sx[grow0];
            out[(size_t)(grow0 + 0) * OUT_F + gcol] = (float)acc[m][n][0] * sx4.x * swv + bv;
            out[(size_t)(grow0 + 1) * OUT_F + gcol] = (float)acc[m][n][1] * sx4.y * swv + bv;
            out[(size_t)(grow0 + 2) * OUT_F + gcol] = (float)acc[m][n][2] * sx4.z * swv + bv;
            out[(size_t)(grow0 + 3) * OUT_F + gcol] = (float)acc[m][n][3] * sx4.w * swv + bv;
        }
    }
}

// ---------- launch ----------
extern "C" void kernel_launch(void* const* d_in, const int* in_sizes, int n_in,
                              void* d_out, int out_size, void* d_ws, size_t ws_size,
                              hipStream_t stream) {
    const float* x         = (const float*)d_in[0];
    const int*   codes     = (const int*)d_in[1];
    const float* codebooks = (const float*)d_in[2];
    const float* scales    = (const float*)d_in[3];
    const float* bias      = (const float*)d_in[4];
    float* out = (float*)d_out;

    // workspace: Wq i8 [OUT_F][IN_F]; Xq i8 [M_TOK][IN_F]; sx; sw (~78.7 MB)
    signed char* Wq = (signed char*)d_ws;
    signed char* Xq = Wq + (size_t)OUT_F * IN_F;
    float* sx = (float*)(Xq + (size_t)M_TOK * IN_F);
    float* sw = sx + M_TOK;

    k_prep<<<M_TOK + OUT_F, 256, 0, stream>>>(x, codes, codebooks, scales,
                                              Xq, sx, Wq, sw);
    // grid: (8192/128) * (11008/256) = 64 * 43 = 2752 blocks, 256 threads
    k_gemm<<<2752, 256, 0, stream>>>(Xq, Wq, sx, sw, bias, out);
}